// Round 6
// baseline (7934.320 us; speedup 1.0000x reference)
//
#include <hip/hip_runtime.h>
#include <math.h>

#define Bsz 32
#define Ssz 512
#define Hsz 1024
#define SLOTS 13   // ring depth; odd & !=0 mod 8 -> stale tags always differ

typedef _Float16 f16x8 __attribute__((ext_vector_type(8)));
typedef float    f32x4 __attribute__((ext_vector_type(4)));
typedef float    f32x8 __attribute__((ext_vector_type(8)));

struct P {
  const float *x, *Wx0, *Wh0, *bx0, *bh0, *Wx1, *Wh1, *bx1, *bh1;
  unsigned short *h0r;    // [13 slot][128 koct][32 b][2 plane][8] f16 frag ring, tag-bearing
  unsigned short *h1r;    // [13 slot][...]
  unsigned *f0, *f1;      // recycle-only epoch flags: f0[13][64], f1[13][64]
  _Float16 *wsw;          // swizzled fp16 weights [2][64 blk][64 ks][4 m][64 lane][8]
  float *out;
};

// fp32 weights -> fp16 MFMA A-frag order; also pre-fills rings with a tag
// pattern (0x70003000) that fails validation for EVERY step (alternating
// bit14 kills hi-parity check; alternating bits14:12 kills lo-tag check).
__global__ __launch_bounds__(256) void preconv(P p) {
  unsigned idx = blockIdx.x * 256 + threadIdx.x;          // < 2^21
  if (idx < 851968u) {                                     // 2 rings * 425984 u32
    if (idx < 425984u) ((unsigned*)p.h0r)[idx] = 0x70003000u;
    else               ((unsigned*)p.h1r)[idx - 425984u] = 0x70003000u;
  }
  unsigned lane  = idx & 63;
  unsigned m     = (idx >> 6) & 3;
  unsigned ks    = (idx >> 8) & 63;
  unsigned blk   = (idx >> 14) & 63;
  unsigned layer = idx >> 20;
  unsigned hidx  = blk * 16 + (lane & 15);
  unsigned k     = ks * 32 + (lane >> 4) * 8;
  unsigned row   = m * 1024 + hidx;
  const float* src;
  if (layer == 0) src = (k < 1024) ? p.Wx0 + (size_t)row * 1024 + k
                                   : p.Wh0 + (size_t)row * 1024 + (k - 1024);
  else            src = (k < 1024) ? p.Wx1 + (size_t)row * 1024 + k
                                   : p.Wh1 + (size_t)row * 1024 + (k - 1024);
  f32x8 v = __builtin_nontemporal_load(reinterpret_cast<const f32x8*>(src));
  f16x8 h;
#pragma unroll
  for (int j = 0; j < 8; ++j) h[j] = (_Float16)v[j];
  *reinterpret_cast<f16x8*>(p.wsw + (size_t)idx * 8) = h;
}

__device__ inline void load_xfrag(const float* xp, f16x8& Bh, f16x8& Bl) {
  f32x8 v = *reinterpret_cast<const f32x8*>(xp);   // cached: 64x reuse across blocks
#pragma unroll
  for (int j = 0; j < 8; ++j) {
    _Float16 hv = (_Float16)v[j];
    Bh[j] = hv; Bl[j] = (_Float16)(v[j] - (float)hv);
  }
}

union U16x8 { f32x4 f; unsigned u[4]; f16x8 h; };

__device__ inline unsigned chk2(f32x4 hf, f32x4 lf, unsigned pp, unsigned tt) {
  U16x8 H, L; H.f = hf; L.f = lf;
  unsigned x = ((H.u[0]^pp)|(H.u[1]^pp)|(H.u[2]^pp)|(H.u[3]^pp)) & 0x40004000u;
  unsigned y = ((L.u[0]^tt)|(L.u[1]^tt)|(L.u[2]^tt)|(L.u[3]^tt)) & 0x70007000u;
  return x | y;
}
__device__ inline f16x8 strip_hi(f32x4 v) {
  U16x8 X; X.f = v;
  X.u[0]&=0xBFFFBFFFu; X.u[1]&=0xBFFFBFFFu; X.u[2]&=0xBFFFBFFFu; X.u[3]&=0xBFFFBFFFu;
  return X.h;
}
__device__ inline f16x8 strip_lo(f32x4 v) {
  U16x8 X; X.f = v;
  X.u[0]&=0x8FFF8FFFu; X.u[1]&=0x8FFF8FFFu; X.u[2]&=0x8FFF8FFFu; X.u[3]&=0x8FFF8FFFu;
  return X.h;
}

// 8 device-scope 16B loads for one 2-kk group (hi/lo x 2 b-tiles x 2 kk)
__device__ inline void issue_group(unsigned long long sb, unsigned voff,
    f32x4& a0, f32x4& a1, f32x4& a2, f32x4& a3,
    f32x4& a4, f32x4& a5, f32x4& a6, f32x4& a7) {
  asm volatile(
    "global_load_dwordx4 %0, %8, %9 offset:-2048 sc0 sc1\n\t"
    "global_load_dwordx4 %1, %8, %9 offset:-2032 sc0 sc1\n\t"
    "global_load_dwordx4 %2, %8, %9 offset:-1536 sc0 sc1\n\t"
    "global_load_dwordx4 %3, %8, %9 offset:-1520 sc0 sc1\n\t"
    "global_load_dwordx4 %4, %8, %9 offset:2048 sc0 sc1\n\t"
    "global_load_dwordx4 %5, %8, %9 offset:2064 sc0 sc1\n\t"
    "global_load_dwordx4 %6, %8, %9 offset:2560 sc0 sc1\n\t"
    "global_load_dwordx4 %7, %8, %9 offset:2576 sc0 sc1"
    : "=&v"(a0), "=&v"(a1), "=&v"(a2), "=&v"(a3),
      "=&v"(a4), "=&v"(a5), "=&v"(a6), "=&v"(a7)
    : "v"(voff), "s"(sb));
}

#define WAITV(N) do { asm volatile("s_waitcnt vmcnt(" #N ")" ::: "memory"); \
                      __builtin_amdgcn_sched_barrier(0); } while (0)

__device__ inline void bar_lds() {   // barrier WITHOUT vmcnt drain
  asm volatile("s_waitcnt lgkmcnt(0)" ::: "memory");
  __builtin_amdgcn_s_barrier();
}

// Persistent pipelined LSTM. Self-validating tag ring: consumer's data load IS
// the synchronization (no flags/fences/drains on the critical path).
__global__ __launch_bounds__(512, 2) void lstm_persist(P p) {
  const int blk   = blockIdx.x;
  const int layer = blk >> 6;
  const int hb    = blk & 63;
  const int tid   = threadIdx.x;
  const int w     = tid >> 6;
  const int lane  = tid & 63;
  const int nl    = lane & 15;
  const int quad  = lane >> 4;

  __shared__ float red[8][64 * 33];
  __shared__ float csl[Bsz * 16];
  __shared__ float bsum[64];

  if (tid < 64) {
    int r = (tid >> 4) * 1024 + hb * 16 + (tid & 15);
    bsum[tid] = layer ? (p.bx1[r] + p.bh1[r]) : (p.bx0[r] + p.bh0[r]);
  }
  csl[tid] = 0.f;
  __syncthreads();

  const _Float16* wslab = p.wsw + (size_t)(layer * 64 + hb) * 131072;
  f16x8 Wr[32];
#pragma unroll
  for (int kk = 0; kk < 8; ++kk)
#pragma unroll
    for (int m = 0; m < 4; ++m)
      Wr[kk * 4 + m] = *reinterpret_cast<const f16x8*>(
          wslab + (size_t)(((w * 8 + kk) * 4 + m) * 64 + lane) * 8);

  const bool xwave = (layer == 0) && (w < 4);
  const int  kloc  = (w & 3) * 256;

  for (int s = 0; s < Ssz; ++s) {
    f32x4 acc[4][2];
#pragma unroll
    for (int m = 0; m < 4; ++m)
#pragma unroll
      for (int nt = 0; nt < 2; ++nt) acc[m][nt] = (f32x4){0.f, 0.f, 0.f, 0.f};

    if (xwave) {
      const float* xbase = p.x + (size_t)s * 1024 + kloc;
      f16x8 Bh[2][2], Bl[2][2];
      load_xfrag(xbase + (size_t)nl        * (Ssz * 1024) + quad * 8, Bh[0][0], Bl[0][0]);
      load_xfrag(xbase + (size_t)(nl + 16) * (Ssz * 1024) + quad * 8, Bh[0][1], Bl[0][1]);
#pragma unroll
      for (int kk = 0; kk < 8; ++kk) {
        const int cur = kk & 1, nxt = cur ^ 1;
        if (kk < 7) {
          const int ko = (kk + 1) * 32 + quad * 8;
          load_xfrag(xbase + (size_t)nl        * (Ssz * 1024) + ko, Bh[nxt][0], Bl[nxt][0]);
          load_xfrag(xbase + (size_t)(nl + 16) * (Ssz * 1024) + ko, Bh[nxt][1], Bl[nxt][1]);
        }
#pragma unroll
        for (int m = 0; m < 4; ++m) {
          f16x8 A = Wr[kk * 4 + m];
#pragma unroll
          for (int nt = 0; nt < 2; ++nt) {
            acc[m][nt] = __builtin_amdgcn_mfma_f32_16x16x32_f16(A, Bh[cur][nt], acc[m][nt], 0, 0, 0);
            acc[m][nt] = __builtin_amdgcn_mfma_f32_16x16x32_f16(A, Bl[cur][nt], acc[m][nt], 0, 0, 0);
          }
        }
      }
    } else {
      // ---- h path: tag-validated device-scope loads, 2-kk-group pipeline ----
      int t; const unsigned short* ringp;
      if (layer == 0)    { t = s - 1; ringp = p.h0r; }
      else if (w < 4)    { t = s;     ringp = p.h0r; }
      else               { t = s - 1; ringp = p.h1r; }
      if (t >= 0) {
        unsigned slot = (unsigned)t % SLOTS;
        unsigned pp = (unsigned)((t & 1) << 14); pp |= pp << 16;
        unsigned tt = (unsigned)((t & 7) << 12); tt |= tt << 16;
        unsigned long long sbv = (unsigned long long)(uintptr_t)ringp
            + (unsigned long long)slot * 131072u + (unsigned)(w & 3) * 32768u + 2048u;
        unsigned sblo = __builtin_amdgcn_readfirstlane((unsigned)sbv);
        unsigned sbhi = __builtin_amdgcn_readfirstlane((unsigned)(sbv >> 32));
        unsigned long long sb = ((unsigned long long)sbhi << 32) | sblo;
        unsigned voff = (unsigned)(quad * 1024 + nl * 32);

        f32x4 A0,A1,A2,A3,A4,A5,A6,A7, B0,B1,B2,B3,B4,B5,B6,B7;
#define CHKA (chk2(A0,A1,pp,tt)|chk2(A2,A3,pp,tt)|chk2(A4,A5,pp,tt)|chk2(A6,A7,pp,tt))
#define CHKB (chk2(B0,B1,pp,tt)|chk2(B2,B3,pp,tt)|chk2(B4,B5,pp,tt)|chk2(B6,B7,pp,tt))
#define RETRYA(OFF) do { unsigned bad_ = CHKA; \
      while (__any((int)(bad_ != 0u))) { \
        issue_group(sb + (OFF), voff, A0,A1,A2,A3,A4,A5,A6,A7); WAITV(0); bad_ = CHKA; } } while (0)
#define RETRYB(OFF) do { unsigned bad_ = CHKB; \
      while (__any((int)(bad_ != 0u))) { \
        issue_group(sb + (OFF), voff, B0,B1,B2,B3,B4,B5,B6,B7); WAITV(0); bad_ = CHKB; } } while (0)
#define DO_KK(KK, Xh0, Xl0, Xh1, Xl1) do { \
      f16x8 bh0_ = strip_hi(Xh0), bl0_ = strip_lo(Xl0); \
      f16x8 bh1_ = strip_hi(Xh1), bl1_ = strip_lo(Xl1); \
      _Pragma("unroll") \
      for (int m_ = 0; m_ < 4; ++m_) { \
        f16x8 Aw_ = Wr[(KK) * 4 + m_]; \
        acc[m_][0] = __builtin_amdgcn_mfma_f32_16x16x32_f16(Aw_, bh0_, acc[m_][0], 0, 0, 0); \
        acc[m_][0] = __builtin_amdgcn_mfma_f32_16x16x32_f16(Aw_, bl0_, acc[m_][0], 0, 0, 0); \
        acc[m_][1] = __builtin_amdgcn_mfma_f32_16x16x32_f16(Aw_, bh1_, acc[m_][1], 0, 0, 0); \
        acc[m_][1] = __builtin_amdgcn_mfma_f32_16x16x32_f16(Aw_, bl1_, acc[m_][1], 0, 0, 0); \
      } } while (0)

        issue_group(sb,         voff, A0,A1,A2,A3,A4,A5,A6,A7);   // kk 0,1
        issue_group(sb + 8192,  voff, B0,B1,B2,B3,B4,B5,B6,B7);   // kk 2,3
        WAITV(8);  RETRYA(0);
        DO_KK(0, A0,A1,A2,A3); DO_KK(1, A4,A5,A6,A7);
        issue_group(sb + 16384, voff, A0,A1,A2,A3,A4,A5,A6,A7);   // kk 4,5
        WAITV(8);  RETRYB(8192);
        DO_KK(2, B0,B1,B2,B3); DO_KK(3, B4,B5,B6,B7);
        issue_group(sb + 24576, voff, B0,B1,B2,B3,B4,B5,B6,B7);   // kk 6,7
        WAITV(8);  RETRYA(16384);
        DO_KK(4, A0,A1,A2,A3); DO_KK(5, A4,A5,A6,A7);
        WAITV(0);  RETRYB(24576);
        DO_KK(6, B0,B1,B2,B3); DO_KK(7, B4,B5,B6,B7);
#undef CHKA
#undef CHKB
#undef RETRYA
#undef RETRYB
#undef DO_KK
      }
    }

    // ---- recycle waits (12-step slack; placed here so old stores are acked) ----
    if (s >= SLOTS) {
      if (layer == 0) {
        const unsigned* a = p.f0 + ((unsigned)(s - 12) % SLOTS) * 64 + lane;
        while (__hip_atomic_load(a, __ATOMIC_RELAXED, __HIP_MEMORY_SCOPE_AGENT) < (unsigned)(s - 11))
          __builtin_amdgcn_s_sleep(2);
        const unsigned* b = p.f1 + ((unsigned)(s - 13) % SLOTS) * 64 + lane;
        while (__hip_atomic_load(b, __ATOMIC_RELAXED, __HIP_MEMORY_SCOPE_AGENT) < (unsigned)(s - 12))
          __builtin_amdgcn_s_sleep(2);
      } else {
        const unsigned* a = p.f1 + ((unsigned)(s - 12) % SLOTS) * 64 + lane;
        while (__hip_atomic_load(a, __ATOMIC_RELAXED, __HIP_MEMORY_SCOPE_AGENT) < (unsigned)(s - 11))
          __builtin_amdgcn_s_sleep(2);
      }
    }

    // ---- reduce: dump all 8 waves, parallel 8-way sum into slab 0 ----
#pragma unroll
    for (int m = 0; m < 4; ++m)
#pragma unroll
      for (int nt = 0; nt < 2; ++nt)
#pragma unroll
        for (int r = 0; r < 4; ++r)
          red[w][(m * 16 + quad * 4 + r) * 33 + nt * 16 + nl] = acc[m][nt][r];
    bar_lds();
#pragma unroll
    for (int j = 0; j < 4; ++j) {
      int idx = tid + j * 512;
      int ad = (idx >> 5) * 33 + (idx & 31);
      float ssum = red[0][ad] + red[1][ad] + red[2][ad] + red[3][ad]
                 + red[4][ad] + red[5][ad] + red[6][ad] + red[7][ad];
      red[0][ad] = ssum;
    }
    bar_lds();

    // ---- pointwise ----
    {
      int hl = tid & 15, b = tid >> 4;
      float gf = red[0][(0 * 16 + hl) * 33 + b] + bsum[0 * 16 + hl];
      float gi = red[0][(1 * 16 + hl) * 33 + b] + bsum[1 * 16 + hl];
      float gg = red[0][(2 * 16 + hl) * 33 + b] + bsum[2 * 16 + hl];
      float go = red[0][(3 * 16 + hl) * 33 + b] + bsum[3 * 16 + hl];
      float f  = 1.f / (1.f + __expf(-gf));
      float i  = 1.f / (1.f + __expf(-gi));
      float g  = tanhf(gg);
      float o  = 1.f / (1.f + __expf(-go));
      float c  = f * csl[b * 16 + hl] + i * g;
      float hn = o * tanhf(c);
      csl[b * 16 + hl] = c;
      _Float16 hh  = (_Float16)hn;
      _Float16 hlo = (_Float16)(hn - (float)hh);
      unsigned short hbits = (unsigned short)(__builtin_bit_cast(unsigned short, hh)
                                              | (unsigned short)((s & 1) << 14));
      unsigned short lbits = (unsigned short)(__builtin_bit_cast(unsigned short, hlo)
                                              | (unsigned short)((s & 7) << 12));
      int hg   = hb * 16 + hl;
      int koct = hb * 2 + (hl >> 3), jj = hl & 7;
      unsigned slot_s = (unsigned)s % SLOTS;
      int fragoff = koct * 512 + b * 16 + jj;
      if (layer == 0) {
        unsigned short* dst = p.h0r + slot_s * 65536 + fragoff;
        __hip_atomic_store(dst,     hbits, __ATOMIC_RELAXED, __HIP_MEMORY_SCOPE_AGENT);
        __hip_atomic_store(dst + 8, lbits, __ATOMIC_RELAXED, __HIP_MEMORY_SCOPE_AGENT);
      } else {
        unsigned short* dst = p.h1r + slot_s * 65536 + fragoff;
        __hip_atomic_store(dst,     hbits, __ATOMIC_RELAXED, __HIP_MEMORY_SCOPE_AGENT);
        __hip_atomic_store(dst + 8, lbits, __ATOMIC_RELAXED, __HIP_MEMORY_SCOPE_AGENT);
        __builtin_nontemporal_store(hn, p.out + (size_t)b * (Ssz * Hsz) + (size_t)s * Hsz + hg);
      }
      if (s == Ssz - 1) {
        float* tail = p.out + (size_t)Bsz * Ssz * Hsz;
        __builtin_nontemporal_store(hn, tail + layer * 32768 + b * 1024 + hg);
        __builtin_nontemporal_store(c,  tail + 65536 + layer * 32768 + b * 1024 + hg);
      }
    }
    bar_lds();
    // recycle flag: "this block finished step s (all its ring reads consumed)"
    if (tid == 0) {
      unsigned slot_s = (unsigned)s % SLOTS;
      if (layer == 0)
        __hip_atomic_store(p.f0 + slot_s * 64 + hb, (unsigned)(s + 1),
                           __ATOMIC_RELAXED, __HIP_MEMORY_SCOPE_AGENT);
      else
        __hip_atomic_store(p.f1 + slot_s * 64 + hb, (unsigned)(s + 1),
                           __ATOMIC_RELAXED, __HIP_MEMORY_SCOPE_AGENT);
    }
  }
}

extern "C" void kernel_launch(void* const* d_in, const int* in_sizes, int n_in,
                              void* d_out, int out_size, void* d_ws, size_t ws_size,
                              hipStream_t stream) {
  char* ws = (char*)d_ws;
  P p;
  p.x   = (const float*)d_in[0];
  p.Wx0 = (const float*)d_in[1]; p.Wh0 = (const float*)d_in[2];
  p.bx0 = (const float*)d_in[3]; p.bh0 = (const float*)d_in[4];
  p.Wx1 = (const float*)d_in[5]; p.Wh1 = (const float*)d_in[6];
  p.bx1 = (const float*)d_in[7]; p.bh1 = (const float*)d_in[8];

  p.h0r = (unsigned short*)(ws);                  // 13*131072B = 1,703,936B
  p.h1r = (unsigned short*)(ws + 2097152);        // 1,703,936B
  p.f0  = (unsigned*)(ws + 4194304);              // 13*64*4 = 3328B
  p.f1  = (unsigned*)(ws + 4198400);              // 3328B
  p.wsw = (_Float16*)(ws + 8388608);              // 32MB
  p.out = (float*)d_out;

  // flags MUST start 0; rings get the never-valid tag pattern from preconv
  hipMemsetAsync(ws + 4194304, 0, 8192, stream);
  preconv<<<dim3(8192), dim3(256), 0, stream>>>(p);
  lstm_persist<<<dim3(128), dim3(512), 0, stream>>>(p);
}

// Round 7
// 7512.486 us; speedup vs baseline: 1.0562x; 1.0562x over previous
//
#include <hip/hip_runtime.h>
#include <math.h>

#define Bsz 32
#define Ssz 512
#define Hsz 1024
#define SLOTS 16   // ring depth; address reuse period = 16 steps

typedef _Float16 f16x8 __attribute__((ext_vector_type(8)));
typedef float    f32x4 __attribute__((ext_vector_type(4)));
typedef float    f32x8 __attribute__((ext_vector_type(8)));

struct P {
  const float *x, *Wx0, *Wh0, *bx0, *bh0, *Wx1, *Wh1, *bx1, *bh1;
  unsigned short *h0r;    // [16 slot][128 koct][32 b][2 plane][8] f16 frag-layout ring
  unsigned short *h1r;    // [16 slot][...]
  unsigned *f0, *f1;      // per-producer epoch flags: f0[16][64], f1[16][64]
  _Float16 *wsw;          // swizzled fp16 weights [2][64 blk][64 ks][4 m][64 lane][8]
  float *out;
};

// fp32 weights -> fp16, swizzled to exact MFMA A-frag order.
// idx bits: lane[0:5] m[6:7] ks[8:13] blk[14:19] layer[20]
__global__ __launch_bounds__(256) void preconv(P p) {
  unsigned idx   = blockIdx.x * 256 + threadIdx.x;        // < 2^21
  unsigned lane  = idx & 63;
  unsigned m     = (idx >> 6) & 3;
  unsigned ks    = (idx >> 8) & 63;
  unsigned blk   = (idx >> 14) & 63;
  unsigned layer = idx >> 20;
  unsigned hidx  = blk * 16 + (lane & 15);
  unsigned k     = ks * 32 + (lane >> 4) * 8;
  unsigned row   = m * 1024 + hidx;
  const float* src;
  if (layer == 0) src = (k < 1024) ? p.Wx0 + (size_t)row * 1024 + k
                                   : p.Wh0 + (size_t)row * 1024 + (k - 1024);
  else            src = (k < 1024) ? p.Wx1 + (size_t)row * 1024 + k
                                   : p.Wh1 + (size_t)row * 1024 + (k - 1024);
  f32x8 v = __builtin_nontemporal_load(reinterpret_cast<const f32x8*>(src));
  f16x8 h;
#pragma unroll
  for (int j = 0; j < 8; ++j) h[j] = (_Float16)v[j];
  *reinterpret_cast<f16x8*>(p.wsw + (size_t)idx * 8) = h;
}

__device__ inline void load_xfrag(const float* xp, f16x8& Bh, f16x8& Bl) {
  f32x8 v = *reinterpret_cast<const f32x8*>(xp);   // cached: 64x reuse across blocks
#pragma unroll
  for (int j = 0; j < 8; ++j) {
    _Float16 hv = (_Float16)v[j];
    Bh[j] = hv; Bl[j] = (_Float16)(v[j] - (float)hv);
  }
}

__device__ inline void bar_lds() {   // barrier WITHOUT vmcnt drain
  asm volatile("s_waitcnt lgkmcnt(0)" ::: "memory");
  __builtin_amdgcn_s_barrier();
}

// Persistent pipelined LSTM, v5 structure + COALESCED ring stores:
// pointwise deposits h into a 2KB LDS ring-image, 2 waves flush it as 128
// full-line global_store_dwordx4 sc0 sc1 (32 clean 64B-line MALL writes per
// block-step instead of 1024 scattered 2B RMWs). out nt-stores moved after
// the flag (no consumer; keep their HBM acks off the critical drain).
__global__ __launch_bounds__(512, 2) void lstm_persist(P p) {
  const int blk   = blockIdx.x;
  const int layer = blk >> 6;
  const int hb    = blk & 63;
  const int tid   = threadIdx.x;
  const int w     = tid >> 6;
  const int lane  = tid & 63;
  const int nl    = lane & 15;
  const int quad  = lane >> 4;

  __shared__ float red[8][64 * 33];   // 67.6KB: one dump slab per wave
  __shared__ float csl[Bsz * 16];     // c state [b][hl]
  __shared__ float bsum[64];          // bx+bh  [gate*16+hl]
  __shared__ unsigned short stage[1024];  // 2KB ring image of this block's slab

  if (tid < 64) {
    int r = (tid >> 4) * 1024 + hb * 16 + (tid & 15);
    bsum[tid] = layer ? (p.bx1[r] + p.bh1[r]) : (p.bx0[r] + p.bh0[r]);
  }
  csl[tid] = 0.f;
  __syncthreads();

  // ---- weights: 32 frags = 128 regs per lane, loaded once ----
  const _Float16* wslab = p.wsw + (size_t)(layer * 64 + hb) * 131072;
  f16x8 Wr[32];
#pragma unroll
  for (int kk = 0; kk < 8; ++kk)
#pragma unroll
    for (int m = 0; m < 4; ++m)
      Wr[kk * 4 + m] = *reinterpret_cast<const f16x8*>(
          wslab + (size_t)(((w * 8 + kk) * 4 + m) * 64 + lane) * 8);

  const bool xwave = (layer == 0) && (w < 4);
  const int  kloc  = (w & 3) * 256;   // k-dim slab base for this wave

  for (int s = 0; s < Ssz; ++s) {
    // ---- per-wave flag polls (relaxed, throttled): one producer per lane ----
    if (layer == 0) {
      if (xwave) {
        if (s >= 16) {  // h0r slot (s&15) reuse: layer-1 must be done with s-16
          const unsigned* fp = p.f1 + (s & 15) * 64 + lane;   // (s-16)&15 == s&15
          unsigned need = (unsigned)(s - 15);
          while (__hip_atomic_load(fp, __ATOMIC_RELAXED, __HIP_MEMORY_SCOPE_AGENT) < need)
            __builtin_amdgcn_s_sleep(2);
        }
      } else if (s >= 1) {  // own-slab layer-0 producers finished s-1
        const unsigned* fp = p.f0 + ((s - 1) & 15) * 64 + (w & 3) * 16 + nl;
        unsigned need = (unsigned)s;
        while (__hip_atomic_load(fp, __ATOMIC_RELAXED, __HIP_MEMORY_SCOPE_AGENT) < need)
          __builtin_amdgcn_s_sleep(2);
      }
    } else {
      if (w < 4) {           // layer-0 slab producers finished s
        const unsigned* fp = p.f0 + (s & 15) * 64 + (w & 3) * 16 + nl;
        unsigned need = (unsigned)(s + 1);
        while (__hip_atomic_load(fp, __ATOMIC_RELAXED, __HIP_MEMORY_SCOPE_AGENT) < need)
          __builtin_amdgcn_s_sleep(2);
      } else if (s >= 1) {   // own-slab layer-1 producers finished s-1
        const unsigned* fp = p.f1 + ((s - 1) & 15) * 64 + (w & 3) * 16 + nl;
        unsigned need = (unsigned)s;
        while (__hip_atomic_load(fp, __ATOMIC_RELAXED, __HIP_MEMORY_SCOPE_AGENT) < need)
          __builtin_amdgcn_s_sleep(2);
      }
    }

    // ---- periodic acquire: invalidate L1/L2 so ≥16-step-old ring copies die.
    //      Between fences, broadcast lines are shared via per-XCD L2. ----
    if (!xwave && ((s & 7) == 0))
      __builtin_amdgcn_fence(__ATOMIC_ACQUIRE, "agent");

    f32x4 acc[4][2];
#pragma unroll
    for (int m = 0; m < 4; ++m)
#pragma unroll
      for (int nt = 0; nt < 2; ++nt) acc[m][nt] = (f32x4){0.f, 0.f, 0.f, 0.f};

    if (xwave) {
      // ---- x path: normal cached loads, double-buffered ----
      const float* xbase = p.x + (size_t)s * 1024 + kloc;
      f16x8 Bh[2][2], Bl[2][2];
      load_xfrag(xbase + (size_t)nl        * (Ssz * 1024) + quad * 8, Bh[0][0], Bl[0][0]);
      load_xfrag(xbase + (size_t)(nl + 16) * (Ssz * 1024) + quad * 8, Bh[0][1], Bl[0][1]);
#pragma unroll
      for (int kk = 0; kk < 8; ++kk) {
        const int cur = kk & 1, nxt = cur ^ 1;
        if (kk < 7) {
          const int ko = (kk + 1) * 32 + quad * 8;
          load_xfrag(xbase + (size_t)nl        * (Ssz * 1024) + ko, Bh[nxt][0], Bl[nxt][0]);
          load_xfrag(xbase + (size_t)(nl + 16) * (Ssz * 1024) + ko, Bh[nxt][1], Bl[nxt][1]);
        }
#pragma unroll
        for (int m = 0; m < 4; ++m) {
          f16x8 A = Wr[kk * 4 + m];
#pragma unroll
          for (int nt = 0; nt < 2; ++nt) {
            acc[m][nt] = __builtin_amdgcn_mfma_f32_16x16x32_f16(A, Bh[cur][nt], acc[m][nt], 0, 0, 0);
            acc[m][nt] = __builtin_amdgcn_mfma_f32_16x16x32_f16(A, Bl[cur][nt], acc[m][nt], 0, 0, 0);
          }
        }
      }
    } else {
      // ---- h path: plain cached 16B fragment loads (L2-shared per XCD) ----
      const unsigned short* rbase;
      if (layer == 0) rbase = p.h0r + ((s - 1) & 15) * 65536;
      else if (w < 4) rbase = p.h0r + (s & 15) * 65536;
      else            rbase = p.h1r + ((s - 1) & 15) * 65536;
      // frag addr (u16): koct*512 + b*16 + plane*8 + j ; koct = kloc/8 + kk*4 + quad
      const _Float16* fb = (const _Float16*)rbase + ((w & 3) * 32 + quad) * 512 + nl * 16;
#pragma unroll
      for (int kk = 0; kk < 8; ++kk) {
        const _Float16* fp2 = fb + kk * 2048;
        f16x8 Bh0 = *reinterpret_cast<const f16x8*>(fp2);        // b=nl,    hi
        f16x8 Bl0 = *reinterpret_cast<const f16x8*>(fp2 + 8);    // b=nl,    lo
        f16x8 Bh1 = *reinterpret_cast<const f16x8*>(fp2 + 256);  // b=nl+16, hi
        f16x8 Bl1 = *reinterpret_cast<const f16x8*>(fp2 + 264);  // b=nl+16, lo
#pragma unroll
        for (int m = 0; m < 4; ++m) {
          f16x8 A = Wr[kk * 4 + m];
          acc[m][0] = __builtin_amdgcn_mfma_f32_16x16x32_f16(A, Bh0, acc[m][0], 0, 0, 0);
          acc[m][0] = __builtin_amdgcn_mfma_f32_16x16x32_f16(A, Bl0, acc[m][0], 0, 0, 0);
          acc[m][1] = __builtin_amdgcn_mfma_f32_16x16x32_f16(A, Bh1, acc[m][1], 0, 0, 0);
          acc[m][1] = __builtin_amdgcn_mfma_f32_16x16x32_f16(A, Bl1, acc[m][1], 0, 0, 0);
        }
      }
    }

    // ---- reduce: dump all 8 waves, parallel 8-way sum into slab 0 ----
#pragma unroll
    for (int m = 0; m < 4; ++m)
#pragma unroll
      for (int nt = 0; nt < 2; ++nt)
#pragma unroll
        for (int r = 0; r < 4; ++r)
          red[w][(m * 16 + quad * 4 + r) * 33 + nt * 16 + nl] = acc[m][nt][r];
    bar_lds();
#pragma unroll
    for (int j = 0; j < 4; ++j) {
      int idx = tid + j * 512;
      int ad = (idx >> 5) * 33 + (idx & 31);
      float ssum = red[0][ad] + red[1][ad] + red[2][ad] + red[3][ad]
                 + red[4][ad] + red[5][ad] + red[6][ad] + red[7][ad];
      red[0][ad] = ssum;
    }
    bar_lds();

    // ---- pointwise: tid -> hl = tid&15, b = tid>>4 ----
    const int hl = tid & 15, b = tid >> 4;
    float hn, cv;
    {
      float gf = red[0][(0 * 16 + hl) * 33 + b] + bsum[0 * 16 + hl];
      float gi = red[0][(1 * 16 + hl) * 33 + b] + bsum[1 * 16 + hl];
      float gg = red[0][(2 * 16 + hl) * 33 + b] + bsum[2 * 16 + hl];
      float go = red[0][(3 * 16 + hl) * 33 + b] + bsum[3 * 16 + hl];
      float f  = 1.f / (1.f + __expf(-gf));
      float i  = 1.f / (1.f + __expf(-gi));
      float g  = tanhf(gg);
      float o  = 1.f / (1.f + __expf(-go));
      cv = f * csl[b * 16 + hl] + i * g;
      hn = o * tanhf(cv);
      csl[b * 16 + hl] = cv;
      _Float16 hh  = (_Float16)hn;
      _Float16 hlo = (_Float16)(hn - (float)hh);
      // deposit into LDS ring image: [koct2][b][plane][jj]
      int sidx = (hl >> 3) * 512 + b * 16 + (hl & 7);
      stage[sidx]     = __builtin_bit_cast(unsigned short, hh);
      stage[sidx + 8] = __builtin_bit_cast(unsigned short, hlo);
    }
    bar_lds();   // stage visible block-wide

    // ---- coalesced ring flush: 2 waves x 64 lanes x dwordx4 = 2KB, full lines ----
    {
      unsigned short* ringb = (layer == 0 ? p.h0r : p.h1r)
                              + ((unsigned)s & 15) * 65536 + hb * 1024;
      if (w < 2) {
        int li = w * 64 + lane;                        // 0..127
        f32x4 d = *reinterpret_cast<const f32x4*>(&stage[li * 8]);
        unsigned long long dst = (unsigned long long)(uintptr_t)(ringb + li * 8);
        asm volatile("global_store_dwordx4 %0, %1, off sc0 sc1"
                     :: "v"(dst), "v"(d) : "memory");
      }
    }
    __syncthreads();   // vmcnt(0) drain of the 128 line-stores + barrier
    if (tid == 0) {
      if (layer == 0)
        __hip_atomic_store(p.f0 + ((unsigned)s & 15) * 64 + hb, (unsigned)(s + 1),
                           __ATOMIC_RELAXED, __HIP_MEMORY_SCOPE_AGENT);
      else
        __hip_atomic_store(p.f1 + ((unsigned)s & 15) * 64 + hb, (unsigned)(s + 1),
                           __ATOMIC_RELAXED, __HIP_MEMORY_SCOPE_AGENT);
    }

    // ---- out stores AFTER the flag: their HBM acks ride the next step ----
    {
      int hg = hb * 16 + hl;
      if (layer == 1)
        __builtin_nontemporal_store(hn, p.out + (size_t)b * (Ssz * Hsz) + (size_t)s * Hsz + hg);
      if (s == Ssz - 1) {
        float* tail = p.out + (size_t)Bsz * Ssz * Hsz;
        __builtin_nontemporal_store(hn, tail + layer * 32768 + b * 1024 + hg);          // h_n
        __builtin_nontemporal_store(cv, tail + 65536 + layer * 32768 + b * 1024 + hg);  // c_n
      }
    }
  }
}

extern "C" void kernel_launch(void* const* d_in, const int* in_sizes, int n_in,
                              void* d_out, int out_size, void* d_ws, size_t ws_size,
                              hipStream_t stream) {
  char* ws = (char*)d_ws;
  P p;
  p.x   = (const float*)d_in[0];
  p.Wx0 = (const float*)d_in[1]; p.Wh0 = (const float*)d_in[2];
  p.bx0 = (const float*)d_in[3]; p.bh0 = (const float*)d_in[4];
  p.Wx1 = (const float*)d_in[5]; p.Wh1 = (const float*)d_in[6];
  p.bx1 = (const float*)d_in[7]; p.bh1 = (const float*)d_in[8];

  p.h0r = (unsigned short*)(ws);                  // 16*65536*2B = 2MB
  p.h1r = (unsigned short*)(ws + 2097152);        // 2MB
  p.f0  = (unsigned*)(ws + 4194304);              // 16*64*4B = 4KB
  p.f1  = (unsigned*)(ws + 4198400);              // 4KB
  p.wsw = (_Float16*)(ws + 8388608);              // 32MB
  p.out = (float*)d_out;

  // zero rings + flags (ws poisoned 0xAA each call; flags MUST start 0,
  // ring slot -1 reads must see h=0)
  hipMemsetAsync(d_ws, 0, 4202496, stream);
  preconv<<<dim3(8192), dim3(256), 0, stream>>>(p);
  lstm_persist<<<dim3(128), dim3(512), 0, stream>>>(p);
}